// Round 3
// baseline (604.530 us; speedup 1.0000x reference)
//
#include <hip/hip_runtime.h>

// DownSample (fp32): fps -> (sparse MLP + max over k), (dense MLP + max over k -> 1x3 s2 conv), coor gather
// Shapes: B=128, n_stk=32, n_stk_pnt=32, COOR=32, m=16, k=2
// outputs: sparse_out [128,256,16] | dense_out [128,128,16,16] | coor_out [128,16,32]
// ws usage: 16 KB only (fps/nn indices at offset 0).

#define BN_SCALE 0.9999950000374997f   // 1/sqrt(1+1e-5)

__device__ __forceinline__ float gelu_f(float x){
  return 0.5f*x*(1.0f + erff(x*0.70710678118654752f));
}

// ---------------- kernel A: FPS + nearest-neighbor + coor_out ----------------
__global__ __launch_bounds__(64) void k_fps(const float* __restrict__ coor,
                                            int* __restrict__ fps_idx,
                                            int* __restrict__ nn_idx,
                                            float* __restrict__ coor_out){
  int b = blockIdx.x;
  __shared__ float X[32][32];
  __shared__ float dist[32];
  __shared__ float nd[32];
  __shared__ int   s_sel[16];
  __shared__ int   s_far;
  int t = threadIdx.x;
  for (int i=t;i<1024;i+=64) X[i>>5][i&31] = coor[b*1024+i];
  if (t<32) dist[t]=3.0e38f;
  if (t==0) s_far=0;
  __syncthreads();
  for (int it=0; it<16; ++it){
    int far = s_far;                       // incoming 'far' is the selected index (scan ys)
    if (t==0){ s_sel[it]=far; fps_idx[b*16+it]=far; }
    if (t<32){
      float d=0.f;
      #pragma unroll
      for (int c=0;c<32;c++){ float df=X[t][c]-X[far][c]; d+=df*df; }
      dist[t]=fminf(dist[t],d);
    }
    __syncthreads();
    if (t==0){
      float best=dist[0]; int bi=0;
      for (int j=1;j<32;j++) if (dist[j]>best){best=dist[j];bi=j;}  // first-max tie-break (argmax)
      s_far=bi;
    }
    __syncthreads();
  }
  // nearest other point for each selected (knn[...,1]; knn[...,0] is self)
  for (int it=0; it<16; ++it){
    int sel = s_sel[it];
    if (t<32){
      float d=0.f;
      #pragma unroll
      for (int c=0;c<32;c++){ float df=X[t][c]-X[sel][c]; d+=df*df; }
      nd[t]=d;
    }
    __syncthreads();
    if (t==0){
      float best=3.0e38f; int bi=0;
      for (int j=0;j<32;j++){ if (j==sel) continue; if (nd[j]<best){best=nd[j];bi=j;} }
      nn_idx[b*16+it]=bi;
    }
    __syncthreads();
  }
  // coor_out: exact passthrough
  for (int q=t;q<512;q+=64){
    int mm=q>>5, c=q&31;
    coor_out[b*512+q] = coor[b*1024 + s_sel[mm]*32 + c];
  }
}

// ---------------- kernel B: sparse branch  out[b,o,m] ----------------
// per (b, o-half): [128x512] x [512x16] with X staged in LDS.
__global__ __launch_bounds__(256) void k_sparse(const float* __restrict__ sfea,
                                                const float* __restrict__ w,
                                                const float* __restrict__ bias,
                                                const float* __restrict__ gg,
                                                const float* __restrict__ bb,
                                                const int* __restrict__ fps_idx,
                                                const int* __restrict__ nn_idx,
                                                float* __restrict__ out){
  int blk=blockIdx.x; int b=blk>>1, oh=blk&1;
  int t=threadIdx.x;
  __shared__ float Xt[16*513];            // [m][i], i<256: (nn - ctr), i>=256: ctr
  __shared__ int s_ci[16], s_ni[16];
  if (t<16){ s_ci[t]=fps_idx[b*16+t]&31; s_ni[t]=nn_idx[b*16+t]&31; }
  __syncthreads();
  const float* sb = sfea + b*256*32 + t*32; // channel t
  for (int m=0;m<16;m++){
    float vc=sb[s_ci[m]];
    float vn=sb[s_ni[m]];
    Xt[m*513 + t]       = vn-vc;
    Xt[m*513 + 256 + t] = vc;
  }
  __syncthreads();
  int oq=t&63, mq=t>>6;
  float accA[2][4]={}, accB[2][4]={};     // A: diff half (i<256), B: center half
  const float* w0p = w + (oh*128 + oq)*512;
  const float* w1p = w + (oh*128 + 64 + oq)*512;
  for (int i=0;i<256;i+=4){
    float4 wv0 = *(const float4*)(w0p + i);
    float4 wv1 = *(const float4*)(w1p + i);
    #pragma unroll
    for (int j=0;j<4;j++){
      float wf0 = ((const float*)&wv0)[j];
      float wf1 = ((const float*)&wv1)[j];
      #pragma unroll
      for (int q=0;q<4;q++){
        float xv = Xt[(mq*4+q)*513 + i + j];
        accA[0][q] += wf0*xv;
        accA[1][q] += wf1*xv;
      }
    }
  }
  for (int i=256;i<512;i+=4){
    float4 wv0 = *(const float4*)(w0p + i);
    float4 wv1 = *(const float4*)(w1p + i);
    #pragma unroll
    for (int j=0;j<4;j++){
      float wf0 = ((const float*)&wv0)[j];
      float wf1 = ((const float*)&wv1)[j];
      #pragma unroll
      for (int q=0;q<4;q++){
        float xv = Xt[(mq*4+q)*513 + i + j];
        accB[0][q] += wf0*xv;
        accB[1][q] += wf1*xv;
      }
    }
  }
  #pragma unroll
  for (int r=0;r<2;r++){
    int o = oh*128 + r*64 + oq;
    float bo=bias[o], go=gg[o], be=bb[o];
    #pragma unroll
    for (int q=0;q<4;q++){
      int m = mq*4+q;
      float k1 = accA[r][q]+accB[r][q]+bo;   // k=1: [nn-ctr | ctr]
      float k0 = accB[r][q]+bo;              // k=0: diff part is exactly 0
      float v = fmaxf(gelu_f(go*(k1*BN_SCALE)+be), gelu_f(go*(k0*BN_SCALE)+be));
      out[(b*256+o)*16+m] = v;
    }
  }
}

// ---------------- kernel C: dense MLP + max_k + 1x3 s2 conv + bn_act, fused per (b,m) ----------------
__global__ __launch_bounds__(256) void k_dense_conv(const float* __restrict__ dfea,
                                                    const float* __restrict__ w,
                                                    const float* __restrict__ bias,
                                                    const float* __restrict__ gg,
                                                    const float* __restrict__ bb,
                                                    const float* __restrict__ wd,
                                                    const float* __restrict__ bias2,
                                                    const float* __restrict__ g2,
                                                    const float* __restrict__ b2,
                                                    const int* __restrict__ fps_idx,
                                                    const int* __restrict__ nn_idx,
                                                    float* __restrict__ out){
  int blk=blockIdx.x; int b=blk>>4, m=blk&15;
  int t=threadIdx.x;
  __shared__ float V[8192];  // phase 1: V[i][p] (256x32). phase 2: S[o][p] stride 36 (128x36=4608)
  int ci=fps_idx[blk]&31, ni=nn_idx[blk]&31;
  const float* Db = dfea + b*131072;        // dfea[b][c][s][x]: c*1024 + s*32 + x
  for (int fp=t; fp<2048; fp+=256){
    int c=fp>>4, xp=fp&15, x=xp*2;
    float2 fc = *(const float2*)(Db + c*1024 + ci*32 + x);
    float2 fn = *(const float2*)(Db + c*1024 + ni*32 + x);
    // i = (x&1)*128 + c ; p = x>>1 (diff cols 0..15), 16+(x>>1) (center cols)
    V[c*32 + xp]            = fn.x-fc.x;
    V[c*32 + 16 + xp]       = fc.x;
    V[(128+c)*32 + xp]      = fn.y-fc.y;
    V[(128+c)*32 + 16 + xp] = fc.y;
  }
  __syncthreads();
  int oq=t&31, pq=t>>5;                     // o in {oq,oq+32,oq+64,oq+96}, p in pq*4..+3
  float acc[4][4]={};
  for (int i=0;i<256;i+=4){
    float4 wv[4];
    #pragma unroll
    for (int r=0;r<4;r++) wv[r] = *(const float4*)(w + (oq+r*32)*256 + i);
    #pragma unroll
    for (int j=0;j<4;j++){
      float4 vv = *(const float4*)&V[(i+j)*32 + pq*4];
      #pragma unroll
      for (int r=0;r<4;r++){
        float wf = ((const float*)&wv[r])[j];
        acc[r][0]+=wf*vv.x; acc[r][1]+=wf*vv.y; acc[r][2]+=wf*vv.z; acc[r][3]+=wf*vv.w;
      }
    }
  }
  __syncthreads();                          // all V reads complete before S overwrites
  #pragma unroll
  for (int r=0;r<4;r++){
    int o=oq+r*32;
    float bo=bias[o], go=gg[o], be=bb[o];
    float a0 = gelu_f(go*(bo*BN_SCALE)+be);   // k=0 value for diff columns (input exactly 0)
    #pragma unroll
    for (int q=0;q<4;q++){
      int p=pq*4+q;
      float val = gelu_f(go*((acc[r][q]+bo)*BN_SCALE)+be);
      if (pq<4) val=fmaxf(val,a0);            // p<16: max over k
      V[o*36 + p] = val;                      // S[o][p]
    }
  }
  __syncthreads();
  // ---- conv: out[o][x] = bn_act( ds_b[o] + sum_c sum_tap wd[o][c][tap] * S[c][2x-1+tap] ) ----
  int o=t&127, xh=t>>7;                     // x = xh*8 + j
  float wacc[8];
  float cb = bias2[o];
  #pragma unroll
  for (int j=0;j<8;j++) wacc[j]=cb;
  const float* wr = wd + o*384;             // ds_w[o][c][0][tap] at c*3+tap
  for (int c=0;c<128;c++){
    float w0=wr[c*3], w1=wr[c*3+1], w2=wr[c*3+2];
    float sv[17];
    sv[0] = xh ? V[c*36+15] : 0.f;          // left pad / cross-half neighbor
    #pragma unroll
    for (int q=0;q<16;q++) sv[1+q] = V[c*36 + xh*16 + q];
    #pragma unroll
    for (int j=0;j<8;j++)
      wacc[j] += w0*sv[2*j] + w1*sv[2*j+1] + w2*sv[2*j+2];
  }
  float g2o=g2[o], b2e=b2[o];
  #pragma unroll
  for (int j=0;j<8;j++){
    out[(b*128+o)*256 + m*16 + xh*8 + j] = gelu_f(g2o*(wacc[j]*BN_SCALE)+b2e);
  }
}

extern "C" void kernel_launch(void* const* d_in, const int* in_sizes, int n_in,
                              void* d_out, int out_size, void* d_ws, size_t ws_size,
                              hipStream_t stream) {
  const float* sparse_fea = (const float*)d_in[0];
  const float* dense_fea  = (const float*)d_in[1];
  const float* stk_coor   = (const float*)d_in[2];
  // d_in[3] = n_stk_center (16, hardcoded)
  const float* sp_w  = (const float*)d_in[4];
  const float* sp_b  = (const float*)d_in[5];
  const float* sp_g  = (const float*)d_in[6];
  const float* sp_be = (const float*)d_in[7];
  const float* dn_w  = (const float*)d_in[8];
  const float* dn_b  = (const float*)d_in[9];
  const float* dn_g  = (const float*)d_in[10];
  const float* dn_be = (const float*)d_in[11];
  const float* ds_w  = (const float*)d_in[12];
  const float* ds_b  = (const float*)d_in[13];
  const float* ds_g  = (const float*)d_in[14];
  const float* ds_be = (const float*)d_in[15];

  float* out = (float*)d_out;
  // outputs: sparse [0, 524288) | dense [524288, 4718592) | coor [4718592, 4784128)
  int* fps_idx = (int*)d_ws;        // 2048 ints
  int* nn_idx  = fps_idx + 2048;    // 2048 ints  (total 16 KB of ws)

  k_fps       <<<128, 64, 0, stream>>>(stk_coor, fps_idx, nn_idx, out + 4718592);
  k_sparse    <<<256, 256, 0, stream>>>(sparse_fea, sp_w, sp_b, sp_g, sp_be, fps_idx, nn_idx, out);
  k_dense_conv<<<2048, 256, 0, stream>>>(dense_fea, dn_w, dn_b, dn_g, dn_be,
                                         ds_w, ds_b, ds_g, ds_be, fps_idx, nn_idx, out + 524288);
}

// Round 4
// 366.304 us; speedup vs baseline: 1.6504x; 1.6504x over previous
//
#include <hip/hip_runtime.h>

// DownSample (fp32): fps -> (sparse MLP + max over k), (dense MLP + max over k -> 1x3 s2 conv), coor gather
// Shapes: B=128, n_stk=32, n_stk_pnt=32, COOR=32, m=16, k=2
// outputs: sparse_out [128,256,16] | dense_out [128,128,16,16] | coor_out [128,16,32]
//
// R3: weights pre-transposed in ws so weight loads are lane-coalesced; outputs
// transposed through LDS before store; k_sparse split to 512 blocks.
// ws usage: 16 KB idx + 868 KB transposed weights.

#define BN_SCALE 0.9999950000374997f   // 1/sqrt(1+1e-5)

__device__ __forceinline__ float gelu_f(float x){
  return 0.5f*x*(1.0f + erff(x*0.70710678118654752f));
}

// ---------------- kernel P: weight transposes (runs every call; ws is re-poisoned) ----
// wt_d[i*128+o]  = dn_w[o*256+i]        (256i x 128o)
// wt_c[(c*3+tap)*128+o] = ds_w[o*384+c*3+tap]   (128c x 3tap x 128o)
// wt_s[i*256+o]  = sp_w[o*512+i]        (512i x 256o)
__global__ __launch_bounds__(256) void k_prep(const float* __restrict__ dn_w,
                                              const float* __restrict__ ds_w,
                                              const float* __restrict__ sp_w,
                                              float* __restrict__ wt_d,
                                              float* __restrict__ wt_c,
                                              float* __restrict__ wt_s){
  int blk = blockIdx.x, t = threadIdx.x;
  if (blk < 128){
    int w = blk*256 + t;               // 0..32767
    int i = w>>7, o = w&127;
    wt_d[w] = dn_w[o*256 + i];
  } else if (blk < 320){
    int w = (blk-128)*256 + t;         // 0..49151
    int o = w&127, ct = w>>7;          // ct = c*3+tap
    wt_c[w] = ds_w[o*384 + ct];
  } else {
    int w = (blk-320)*256 + t;         // 0..131071
    int o = w&255, i = w>>8;
    wt_s[w] = sp_w[o*512 + i];
  }
}

// ---------------- kernel A: FPS + nearest-neighbor + coor_out ----------------
__global__ __launch_bounds__(64) void k_fps(const float* __restrict__ coor,
                                            int* __restrict__ fps_idx,
                                            int* __restrict__ nn_idx,
                                            float* __restrict__ coor_out){
  int b = blockIdx.x;
  __shared__ float X[32][32];
  __shared__ float dist[32];
  __shared__ float nd[32];
  __shared__ int   s_sel[16];
  __shared__ int   s_far;
  int t = threadIdx.x;
  for (int i=t;i<1024;i+=64) X[i>>5][i&31] = coor[b*1024+i];
  if (t<32) dist[t]=3.0e38f;
  if (t==0) s_far=0;
  __syncthreads();
  for (int it=0; it<16; ++it){
    int far = s_far;                       // incoming 'far' is the selected index (scan ys)
    if (t==0){ s_sel[it]=far; fps_idx[b*16+it]=far; }
    if (t<32){
      float d=0.f;
      #pragma unroll
      for (int c=0;c<32;c++){ float df=X[t][c]-X[far][c]; d+=df*df; }
      dist[t]=fminf(dist[t],d);
    }
    __syncthreads();
    if (t==0){
      float best=dist[0]; int bi=0;
      for (int j=1;j<32;j++) if (dist[j]>best){best=dist[j];bi=j;}  // first-max tie-break (argmax)
      s_far=bi;
    }
    __syncthreads();
  }
  // nearest other point for each selected (knn[...,1]; knn[...,0] is self)
  for (int it=0; it<16; ++it){
    int sel = s_sel[it];
    if (t<32){
      float d=0.f;
      #pragma unroll
      for (int c=0;c<32;c++){ float df=X[t][c]-X[sel][c]; d+=df*df; }
      nd[t]=d;
    }
    __syncthreads();
    if (t==0){
      float best=3.0e38f; int bi=0;
      for (int j=0;j<32;j++){ if (j==sel) continue; if (nd[j]<best){best=nd[j];bi=j;} }
      nn_idx[b*16+it]=bi;
    }
    __syncthreads();
  }
  for (int q=t;q<512;q+=64){
    int mm=q>>5, c=q&31;
    coor_out[b*512+q] = coor[b*1024 + s_sel[mm]*32 + c];
  }
}

// ---------------- kernel B: sparse branch  out[b,o,m] ----------------
// block = (b, mg) with mg = 4 m's. thread: o4=(t&63)*4 (4 contiguous o), mloc=t>>6.
__global__ __launch_bounds__(256) void k_sparse(const float* __restrict__ sfea,
                                                const float* __restrict__ wt_s,
                                                const float* __restrict__ bias,
                                                const float* __restrict__ gg,
                                                const float* __restrict__ bb,
                                                const int* __restrict__ fps_idx,
                                                const int* __restrict__ nn_idx,
                                                float* __restrict__ out){
  int blk=blockIdx.x; int b=blk>>2, mg=blk&3;
  int t=threadIdx.x;
  __shared__ float Xt[4*520];             // [mloc][i], i<256: (nn-ctr), i>=256: ctr
  __shared__ int s_ci[4], s_ni[4];
  if (t<4){ s_ci[t]=fps_idx[b*16+mg*4+t]&31; s_ni[t]=nn_idx[b*16+mg*4+t]&31; }
  __syncthreads();
  {
    const float* sb = sfea + b*8192 + t*32;  // channel t
    #pragma unroll
    for (int ml=0;ml<4;ml++){
      float vc=sb[s_ci[ml]];
      float vn=sb[s_ni[ml]];
      Xt[ml*520 + t]       = vn-vc;
      Xt[ml*520 + 256 + t] = vc;
    }
  }
  __syncthreads();
  int oq=t&63, mloc=t>>6;
  int o4=oq*4;
  float accA[4]={}, accB[4]={};
  const float* xr = &Xt[mloc*520];
  #pragma unroll 4
  for (int i=0;i<256;i++){
    float4 wv = *(const float4*)(wt_s + i*256 + o4);   // lane-coalesced 1KB/instr
    float xv = xr[i];
    accA[0]+=wv.x*xv; accA[1]+=wv.y*xv; accA[2]+=wv.z*xv; accA[3]+=wv.w*xv;
  }
  #pragma unroll 4
  for (int i=256;i<512;i++){
    float4 wv = *(const float4*)(wt_s + i*256 + o4);
    float xv = xr[i];
    accB[0]+=wv.x*xv; accB[1]+=wv.y*xv; accB[2]+=wv.z*xv; accB[3]+=wv.w*xv;
  }
  __syncthreads();                         // Xt no longer needed; reuse as To
  float* To = Xt;                          // To[o*5 + mloc], 256*5=1280 floats
  #pragma unroll
  for (int r=0;r<4;r++){
    int o=o4+r;
    float bo=bias[o], go=gg[o], be=bb[o];
    float k1 = accA[r]+accB[r]+bo;         // k=1: [nn-ctr | ctr]
    float k0 = accB[r]+bo;                 // k=0: diff part exactly 0
    To[o*5+mloc] = fmaxf(gelu_f(go*(k1*BN_SCALE)+be), gelu_f(go*(k0*BN_SCALE)+be));
  }
  __syncthreads();
  // coalesced-ish store: out[(b*256+o)*16 + mg*4 + ml]
  #pragma unroll
  for (int k2=0;k2<4;k2++){
    int q = t + k2*256;                    // 0..1023
    int o = q>>2, ml = q&3;
    out[(b*256+o)*16 + mg*4 + ml] = To[o*5+ml];
  }
}

// ---------------- kernel C: dense MLP + max_k + 1x3 s2 conv + bn_act, fused per (b,m) ----------------
__global__ __launch_bounds__(256) void k_dense_conv(const float* __restrict__ dfea,
                                                    const float* __restrict__ wt_d,
                                                    const float* __restrict__ bias,
                                                    const float* __restrict__ gg,
                                                    const float* __restrict__ bb,
                                                    const float* __restrict__ wt_c,
                                                    const float* __restrict__ bias2,
                                                    const float* __restrict__ g2,
                                                    const float* __restrict__ b2,
                                                    const int* __restrict__ fps_idx,
                                                    const int* __restrict__ nn_idx,
                                                    float* __restrict__ out){
  int blk=blockIdx.x; int b=blk>>4, m=blk&15;
  int t=threadIdx.x;
  __shared__ float V[8192];  // ph1: V[i][p] 256x32 (32KB). ph2: S[o*33+p] (0..4223). ph3: T at 4352.
  int ci=fps_idx[blk]&31, ni=nn_idx[blk]&31;
  const float* Db = dfea + b*131072;        // dfea[b][c][s][x]: c*1024 + s*32 + x
  for (int fp=t; fp<2048; fp+=256){
    int c=fp>>4, xp=fp&15, x=xp*2;
    float2 fc = *(const float2*)(Db + c*1024 + ci*32 + x);
    float2 fn = *(const float2*)(Db + c*1024 + ni*32 + x);
    // i = (x&1)*128 + c ; p = x>>1 (diff cols 0..15), 16+(x>>1) (center cols)
    V[c*32 + xp]            = fn.x-fc.x;
    V[c*32 + 16 + xp]       = fc.x;
    V[(128+c)*32 + xp]      = fn.y-fc.y;
    V[(128+c)*32 + 16 + xp] = fc.y;
  }
  __syncthreads();
  int oq=t&31, pq=t>>5;                     // o = oq*4+r (contiguous), p = pq*4+q
  int o4 = oq*4;
  float acc[4][4]={};
  #pragma unroll 4
  for (int i=0;i<256;i++){
    float4 wv = *(const float4*)(wt_d + i*128 + o4);   // lane-coalesced 512B/instr
    float4 vv = *(const float4*)&V[i*32 + pq*4];       // broadcast per pq group
    acc[0][0]+=wv.x*vv.x; acc[0][1]+=wv.x*vv.y; acc[0][2]+=wv.x*vv.z; acc[0][3]+=wv.x*vv.w;
    acc[1][0]+=wv.y*vv.x; acc[1][1]+=wv.y*vv.y; acc[1][2]+=wv.y*vv.z; acc[1][3]+=wv.y*vv.w;
    acc[2][0]+=wv.z*vv.x; acc[2][1]+=wv.z*vv.y; acc[2][2]+=wv.z*vv.z; acc[2][3]+=wv.z*vv.w;
    acc[3][0]+=wv.w*vv.x; acc[3][1]+=wv.w*vv.y; acc[3][2]+=wv.w*vv.z; acc[3][3]+=wv.w*vv.w;
  }
  __syncthreads();                          // all V reads complete before S overwrites
  #pragma unroll
  for (int r=0;r<4;r++){
    int o=o4+r;
    float bo=bias[o], go=gg[o], be=bb[o];
    float a0 = gelu_f(go*(bo*BN_SCALE)+be);   // k=0 value for diff columns (input exactly 0)
    #pragma unroll
    for (int q=0;q<4;q++){
      int p=pq*4+q;
      float val = gelu_f(go*((acc[r][q]+bo)*BN_SCALE)+be);
      if (pq<4) val=fmaxf(val,a0);            // p<16: max over k
      V[o*33 + p] = val;                      // S[o][p]
    }
  }
  __syncthreads();
  // ---- conv: out[o][x] = bn_act( ds_b[o] + sum_c sum_tap wd[o][c][tap] * S[c][2x-1+tap] ) ----
  int o=t&127, xh=t>>7;                     // x = xh*8 + j
  float wacc[8];
  float cb = bias2[o];
  #pragma unroll
  for (int j=0;j<8;j++) wacc[j]=cb;
  float* T = V + 4352;                      // T[o*17 + x], 128*17=2176
  #pragma unroll 2
  for (int c=0;c<128;c++){
    float w0 = wt_c[c*384 +       o];       // lane-coalesced 512B/instr
    float w1 = wt_c[c*384 + 128 + o];
    float w2 = wt_c[c*384 + 256 + o];
    const float* Sr = &V[c*33 + xh*16];
    float sv[17];
    sv[0] = xh ? V[c*33+15] : 0.f;          // left pad / cross-half neighbor
    #pragma unroll
    for (int q=0;q<16;q++) sv[1+q] = Sr[q]; // broadcast reads (free)
    #pragma unroll
    for (int j=0;j<8;j++)
      wacc[j] += w0*sv[2*j] + w1*sv[2*j+1] + w2*sv[2*j+2];
  }
  float g2o=g2[o], b2e=b2[o];
  #pragma unroll
  for (int j=0;j<8;j++)
    T[o*17 + xh*8 + j] = gelu_f(g2o*(wacc[j]*BN_SCALE)+b2e);
  __syncthreads();
  // coalesced-ish store: out[(b*128+o)*256 + m*16 + x]
  #pragma unroll
  for (int k2=0;k2<8;k2++){
    int q = t + k2*256;                     // 0..2047
    int oo = q>>4, x = q&15;
    out[(b*128+oo)*256 + m*16 + x] = T[oo*17+x];
  }
}

extern "C" void kernel_launch(void* const* d_in, const int* in_sizes, int n_in,
                              void* d_out, int out_size, void* d_ws, size_t ws_size,
                              hipStream_t stream) {
  const float* sparse_fea = (const float*)d_in[0];
  const float* dense_fea  = (const float*)d_in[1];
  const float* stk_coor   = (const float*)d_in[2];
  // d_in[3] = n_stk_center (16, hardcoded)
  const float* sp_w  = (const float*)d_in[4];
  const float* sp_b  = (const float*)d_in[5];
  const float* sp_g  = (const float*)d_in[6];
  const float* sp_be = (const float*)d_in[7];
  const float* dn_w  = (const float*)d_in[8];
  const float* dn_b  = (const float*)d_in[9];
  const float* dn_g  = (const float*)d_in[10];
  const float* dn_be = (const float*)d_in[11];
  const float* ds_w  = (const float*)d_in[12];
  const float* ds_b  = (const float*)d_in[13];
  const float* ds_g  = (const float*)d_in[14];
  const float* ds_be = (const float*)d_in[15];

  float* out = (float*)d_out;
  // outputs: sparse [0, 524288) | dense [524288, 4718592) | coor [4718592, 4784128)
  int*   fps_idx = (int*)d_ws;              // [0, 2048) ints
  int*   nn_idx  = fps_idx + 2048;          // [2048, 4096) ints
  float* wsf     = (float*)d_ws;
  float* wt_d    = wsf + 4096;              // 32768 floats
  float* wt_c    = wsf + 36864;             // 49152 floats
  float* wt_s    = wsf + 86016;             // 131072 floats (end 217088 = 868KB)

  k_prep      <<<832, 256, 0, stream>>>(dn_w, ds_w, sp_w, wt_d, wt_c, wt_s);
  k_fps       <<<128, 64, 0, stream>>>(stk_coor, fps_idx, nn_idx, out + 4718592);
  k_sparse    <<<512, 256, 0, stream>>>(sparse_fea, wt_s, sp_b, sp_g, sp_be, fps_idx, nn_idx, out);
  k_dense_conv<<<2048, 256, 0, stream>>>(dense_fea, wt_d, dn_b, dn_g, dn_be,
                                         wt_c, ds_b, ds_g, ds_be, fps_idx, nn_idx, out + 524288);
}

// Round 5
// 208.209 us; speedup vs baseline: 2.9035x; 1.7593x over previous
//
#include <hip/hip_runtime.h>

// DownSample (fp32 in/out, bf16 MFMA internals), MI355X gfx950
// Shapes: B=128, n_stk=32, n_stk_pnt=32, COOR=32, m=16, k=2
// outputs: sparse_out [128,256,16] | dense_out [128,128,16,16] | coor_out [128,16,32]
//
// R5: all matmuls on v_mfma_f32_16x16x32_bf16. Weights pre-swizzled to the
// A-fragment layout (o=lane&15, k=quad*8+j) in ws as bf16 by k_prep_fps.

typedef unsigned short u16;
typedef unsigned int   u32;
typedef __attribute__((ext_vector_type(8))) short bf16x8;   // 4 VGPRs
typedef __attribute__((ext_vector_type(4))) float f32x4;

#define BN_SCALE 0.9999950000374997f   // 1/sqrt(1+1e-5)

__device__ __forceinline__ float gelu_f(float x){
  return 0.5f*x*(1.0f + erff(x*0.70710678118654752f));
}
__device__ __forceinline__ u16 f2bf(float f){
  u32 x = __float_as_uint(f);
  x += 0x7fffu + ((x>>16)&1u);           // RNE
  return (u16)(x>>16);
}

// ---------------- kernel 1: weight swizzle+bf16 (blocks 0..831) + FPS (blocks 832..959) ----
// A-frag layout: afrag[(kt*NT + ot)*64 + lane][j] = W[o = ot*16+(lane&15)][k = kt*32+(lane>>4)*8+j]
__global__ __launch_bounds__(256) void k_prep_fps(
    const float* __restrict__ dn_w, const float* __restrict__ ds_w, const float* __restrict__ sp_w,
    const float* __restrict__ coor,
    u16* __restrict__ wdb, u16* __restrict__ wcb, u16* __restrict__ wsb,
    int* __restrict__ fps_idx, int* __restrict__ nn_idx, float* __restrict__ coor_out)
{
  int blk = blockIdx.x, t = threadIdx.x;
  if (blk < 128){                       // dense MLP W [128o x 256k] -> 8kt x 8ot
    int w = blk*256 + t;
    int j=w&7, lane=(w>>3)&63, tile=w>>9;
    int kt=tile>>3, ot=tile&7;
    int o=ot*16+(lane&15), i=kt*32+(lane>>4)*8+j;
    wdb[w] = f2bf(dn_w[o*256+i]);
  } else if (blk < 320){                // conv W [128o x 384k] -> 12kt x 8ot
    int w = (blk-128)*256 + t;
    int j=w&7, lane=(w>>3)&63, tile=w>>9;
    int kt=tile>>3, ot=tile&7;
    int o=ot*16+(lane&15), k=kt*32+(lane>>4)*8+j;
    wcb[w] = f2bf(ds_w[o*384+k]);
  } else if (blk < 832){                // sparse W [256o x 512k] -> 16kt x 16ot
    int w = (blk-320)*256 + t;
    int j=w&7, lane=(w>>3)&63, tile=w>>9;
    int kt=tile>>4, ot=tile&15;
    int o=ot*16+(lane&15), i=kt*32+(lane>>4)*8+j;
    wsb[w] = f2bf(sp_w[o*512+i]);
  } else {
    // ---- FPS + nearest-neighbor + coor_out for b = blk-832 ----
    int b = blk - 832;
    __shared__ float X[32][32];
    __shared__ float dist[32];
    __shared__ float nd[32];
    __shared__ int   s_sel[16];
    __shared__ int   s_far;
    for (int i=t;i<1024;i+=256) X[i>>5][i&31] = coor[b*1024+i];
    if (t<32) dist[t]=3.0e38f;
    if (t==0) s_far=0;
    __syncthreads();
    for (int it=0; it<16; ++it){
      int far = s_far;                   // incoming 'far' is the selected index (scan ys)
      if (t==0){ s_sel[it]=far; fps_idx[b*16+it]=far; }
      if (t<32){
        float d=0.f;
        #pragma unroll
        for (int c=0;c<32;c++){ float df=X[t][c]-X[far][c]; d+=df*df; }
        dist[t]=fminf(dist[t],d);
      }
      __syncthreads();
      if (t==0){
        float best=dist[0]; int bi=0;
        for (int j=1;j<32;j++) if (dist[j]>best){best=dist[j];bi=j;}  // first-max tie-break
        s_far=bi;
      }
      __syncthreads();
    }
    for (int it=0; it<16; ++it){
      int sel = s_sel[it];
      if (t<32){
        float d=0.f;
        #pragma unroll
        for (int c=0;c<32;c++){ float df=X[t][c]-X[sel][c]; d+=df*df; }
        nd[t]=d;
      }
      __syncthreads();
      if (t==0){
        float best=3.0e38f; int bi=0;
        for (int j=0;j<32;j++){ if (j==sel) continue; if (nd[j]<best){best=nd[j];bi=j;} }
        nn_idx[b*16+it]=bi;
      }
      __syncthreads();
    }
    for (int q=t;q<512;q+=256){
      int mm=q>>5, c=q&31;
      coor_out[b*512+q] = coor[b*1024 + s_sel[mm]*32 + c];
    }
  }
}

// ---------------- kernel 2: sparse branch, MFMA ----------------
// block = (b, o-half). C = W[128o x 512i] * X[512i x 16m]; accA = diff half, accB = ctr half.
__global__ __launch_bounds__(256) void k_sparse(
    const float* __restrict__ sfea, const u16* __restrict__ wsb,
    const float* __restrict__ bias, const float* __restrict__ gg, const float* __restrict__ bb,
    const int* __restrict__ fps_idx, const int* __restrict__ nn_idx, float* __restrict__ out)
{
  int blk=blockIdx.x; int b=blk>>1, oh=blk&1;
  int t=threadIdx.x, lane=t&63, wv=t>>6, quad=lane>>4, col=lane&15;
  __shared__ u16 Xb[16*520];            // [m][i], stride 520 (512+8 pad)
  __shared__ float Pb[256], Pg[256], Pe[256];
  __shared__ int s_ci[16], s_ni[16];
  if (t<16){ s_ci[t]=fps_idx[b*16+t]&31; s_ni[t]=nn_idx[b*16+t]&31; }
  Pb[t]=bias[t]; Pg[t]=gg[t]; Pe[t]=bb[t];
  __syncthreads();
  const float* row = sfea + b*8192 + t*32;   // channel t
  #pragma unroll
  for (int m=0;m<16;m++){
    float vc=row[s_ci[m]], vn=row[s_ni[m]];
    Xb[m*520 + t]       = f2bf(vn-vc);       // i<256: diff
    Xb[m*520 + 256 + t] = f2bf(vc);          // i>=256: ctr
  }
  __syncthreads();
  f32x4 accA[2]={}, accB[2]={};
  for (int kt=0;kt<8;kt++){                  // diff half
    bf16x8 bfr = *(const bf16x8*)&Xb[col*520 + kt*32 + quad*8];
    #pragma unroll
    for (int r=0;r<2;r++){
      int ot = oh*8 + wv + r*4;
      bf16x8 afr = *(const bf16x8*)&wsb[((kt*16+ot)*64+lane)*8];
      accA[r]=__builtin_amdgcn_mfma_f32_16x16x32_bf16(afr,bfr,accA[r],0,0,0);
    }
  }
  for (int kt=8;kt<16;kt++){                 // ctr half
    bf16x8 bfr = *(const bf16x8*)&Xb[col*520 + kt*32 + quad*8];
    #pragma unroll
    for (int r=0;r<2;r++){
      int ot = oh*8 + wv + r*4;
      bf16x8 afr = *(const bf16x8*)&wsb[((kt*16+ot)*64+lane)*8];
      accB[r]=__builtin_amdgcn_mfma_f32_16x16x32_bf16(afr,bfr,accB[r],0,0,0);
    }
  }
  #pragma unroll
  for (int r=0;r<2;r++){
    #pragma unroll
    for (int reg=0;reg<4;reg++){
      int o = oh*128 + (wv+r*4)*16 + quad*4 + reg;
      float bo=Pb[o], go=Pg[o], be=Pe[o];
      float k1 = accA[r][reg]+accB[r][reg]+bo;  // k=1: [diff|ctr]
      float k0 = accB[r][reg]+bo;               // k=0: diff part exactly 0
      float v = fmaxf(gelu_f(go*(k1*BN_SCALE)+be), gelu_f(go*(k0*BN_SCALE)+be));
      out[(b*256+o)*16 + col] = v;
    }
  }
}

// ---------------- kernel 3: dense MLP + max_k + im2col + 1x3 s2 conv, MFMA, per (b,m) ----------------
__global__ __launch_bounds__(256) void k_dense_conv(
    const float* __restrict__ dfea, const u16* __restrict__ wdb,
    const float* __restrict__ bias, const float* __restrict__ gg, const float* __restrict__ bb,
    const u16* __restrict__ wcb, const float* __restrict__ bias2,
    const float* __restrict__ g2, const float* __restrict__ b2,
    const int* __restrict__ fps_idx, const int* __restrict__ nn_idx, float* __restrict__ out)
{
  int blk=blockIdx.x; int b=blk>>4, m=blk&15;
  int t=threadIdx.x, lane=t&63, wv=t>>6, quad=lane>>4, col=lane&15;
  __shared__ char smem[20480];
  u16* Vb = (u16*)smem;                 // phase 1: [32p][264] bf16 (16896 B)
  u16* Bc = (u16*)smem;                 // phase 2: [16x][392] bf16 im2col (12544 B, overlaps)
  float* P = (float*)(smem+16896);      // dn_b|dn_g|dn_be|ds_b|ds_g|ds_be|a0s, 7x128 f32
  int ci=fps_idx[blk]&31, ni=nn_idx[blk]&31;
  const float* Db = dfea + b*131072;    // dfea[b][c][s][x]: c*1024 + s*32 + x
  if (t<128){
    P[t]=bias[t]; P[128+t]=gg[t]; P[256+t]=bb[t];
    P[384+t]=bias2[t]; P[512+t]=g2[t]; P[640+t]=b2[t];
  }
  for (int fp=t; fp<2048; fp+=256){
    int c=fp>>4, xp=fp&15, x=xp*2;
    float2 fc = *(const float2*)(Db + c*1024 + ci*32 + x);
    float2 fn = *(const float2*)(Db + c*1024 + ni*32 + x);
    // Vb[p][i]: p<16 diff at x'=2p+(i>>7), p>=16 ctr; i = (x&1)*128 + c
    Vb[xp*264 + c]            = f2bf(fn.x-fc.x);
    Vb[(16+xp)*264 + c]       = f2bf(fc.x);
    Vb[xp*264 + 128 + c]      = f2bf(fn.y-fc.y);
    Vb[(16+xp)*264 + 128 + c] = f2bf(fc.y);
  }
  __syncthreads();
  if (t<128) P[768+t] = gelu_f(P[128+t]*(P[t]*BN_SCALE)+P[256+t]);  // a0s[o] (k=0 diff value)
  // ---- dense MLP: C[128o x 32p], wave: otiles {wv, wv+4}, ptiles {0,1} ----
  f32x4 acc[2][2]={};
  for (int kt=0;kt<8;kt++){
    bf16x8 b0 = *(const bf16x8*)&Vb[ col     *264 + kt*32 + quad*8];
    bf16x8 b1 = *(const bf16x8*)&Vb[(16+col) *264 + kt*32 + quad*8];
    #pragma unroll
    for (int r=0;r<2;r++){
      int ot=wv+r*4;
      bf16x8 afr = *(const bf16x8*)&wdb[((kt*8+ot)*64+lane)*8];
      acc[r][0]=__builtin_amdgcn_mfma_f32_16x16x32_bf16(afr,b0,acc[r][0],0,0,0);
      acc[r][1]=__builtin_amdgcn_mfma_f32_16x16x32_bf16(afr,b1,acc[r][1],0,0,0);
    }
  }
  __syncthreads();                       // Vb dead -> reuse as Bc
  for (int q=t; q<3136; q+=256) ((u32*)Bc)[q]=0u;   // zero im2col (left pad x=0 tap0)
  __syncthreads();
  // ---- epilogue 1: bn+gelu+max_k, scatter S[o][p] into im2col Bc[x][o*3+tap] ----
  #pragma unroll
  for (int r=0;r<2;r++){
    #pragma unroll
    for (int pt=0;pt<2;pt++){
      #pragma unroll
      for (int reg=0;reg<4;reg++){
        int o = (wv+r*4)*16 + quad*4 + reg;
        int p = pt*16 + col;
        float bo=P[o], go=P[128+o], be=P[256+o];
        float val = gelu_f(go*((acc[r][pt][reg]+bo)*BN_SCALE)+be);
        if (pt==0) val = fmaxf(val, P[768+o]);     // p<16: max over k
        u16 bv = f2bf(val);
        // S[c=o][p] feeds conv taps: 2x-1+tap == p
        if (p&1){
          Bc[((p-1)>>1)*392 + o*3 + 2] = bv;
          if (p<31) Bc[((p+1)>>1)*392 + o*3 + 0] = bv;
        } else {
          Bc[(p>>1)*392 + o*3 + 1] = bv;
        }
      }
    }
  }
  __syncthreads();
  // ---- conv: C[128o x 16x] = Wc[128o x 384k] * Bc[384k x 16x] ----
  f32x4 cacc[2]={};
  for (int kt=0;kt<12;kt++){
    bf16x8 bfr = *(const bf16x8*)&Bc[col*392 + kt*32 + quad*8];
    #pragma unroll
    for (int r=0;r<2;r++){
      int ot=wv+r*4;
      bf16x8 afr = *(const bf16x8*)&wcb[((kt*8+ot)*64+lane)*8];
      cacc[r]=__builtin_amdgcn_mfma_f32_16x16x32_bf16(afr,bfr,cacc[r],0,0,0);
    }
  }
  #pragma unroll
  for (int r=0;r<2;r++){
    #pragma unroll
    for (int reg=0;reg<4;reg++){
      int o = (wv+r*4)*16 + quad*4 + reg;
      float cb=P[384+o], go=P[512+o], be=P[640+o];
      float val = gelu_f(go*((cacc[r][reg]+cb)*BN_SCALE)+be);
      out[(b*128+o)*256 + m*16 + col] = val;
    }
  }
}

extern "C" void kernel_launch(void* const* d_in, const int* in_sizes, int n_in,
                              void* d_out, int out_size, void* d_ws, size_t ws_size,
                              hipStream_t stream) {
  const float* sparse_fea = (const float*)d_in[0];
  const float* dense_fea  = (const float*)d_in[1];
  const float* stk_coor   = (const float*)d_in[2];
  // d_in[3] = n_stk_center (16, hardcoded)
  const float* sp_w  = (const float*)d_in[4];
  const float* sp_b  = (const float*)d_in[5];
  const float* sp_g  = (const float*)d_in[6];
  const float* sp_be = (const float*)d_in[7];
  const float* dn_w  = (const float*)d_in[8];
  const float* dn_b  = (const float*)d_in[9];
  const float* dn_g  = (const float*)d_in[10];
  const float* dn_be = (const float*)d_in[11];
  const float* ds_w  = (const float*)d_in[12];
  const float* ds_b  = (const float*)d_in[13];
  const float* ds_g  = (const float*)d_in[14];
  const float* ds_be = (const float*)d_in[15];

  float* out = (float*)d_out;
  // outputs: sparse [0, 524288) | dense [524288, 4718592) | coor [4718592, 4784128)
  int* fps_idx = (int*)d_ws;                              // [0, 8192) B
  int* nn_idx  = fps_idx + 2048;
  u16* wdb = (u16*)((char*)d_ws + 16384);                 // 64 KB  (8kt x 8ot)
  u16* wcb = (u16*)((char*)d_ws + 81920);                 // 96 KB  (12kt x 8ot)
  u16* wsb = (u16*)((char*)d_ws + 180224);                // 256 KB (16kt x 16ot)

  k_prep_fps  <<<960, 256, 0, stream>>>(dn_w, ds_w, sp_w, stk_coor,
                                        wdb, wcb, wsb, fps_idx, nn_idx, out + 4718592);
  k_sparse    <<<256, 256, 0, stream>>>(sparse_fea, wsb, sp_b, sp_g, sp_be,
                                        fps_idx, nn_idx, out);
  k_dense_conv<<<2048, 256, 0, stream>>>(dense_fea, wdb, dn_b, dn_g, dn_be,
                                         wcb, ds_b, ds_g, ds_be, fps_idx, nn_idx, out + 524288);
}

// Round 6
// 179.465 us; speedup vs baseline: 3.3685x; 1.1602x over previous
//
#include <hip/hip_runtime.h>

// DownSample (fp32 in/out, bf16 MFMA internals), MI355X gfx950
// Shapes: B=128, n_stk=32, n_stk_pnt=32, COOR=32, m=16, k=2
// outputs: sparse_out [128,256,16] | dense_out [128,128,16,16] | coor_out [128,16,32]
//
// R6: wave-parallel shuffle FPS (was 50us serial); sparse+dense fused into one
// kernel so they overlap. All matmuls on v_mfma_f32_16x16x32_bf16 with weights
// pre-swizzled to A-fragment layout in ws.

typedef unsigned short u16;
typedef unsigned int   u32;
typedef __attribute__((ext_vector_type(8))) short bf16x8;   // 4 VGPRs
typedef __attribute__((ext_vector_type(4))) float f32x4;

#define BN_SCALE 0.9999950000374997f   // 1/sqrt(1+1e-5)

__device__ __forceinline__ float gelu_f(float x){
  return 0.5f*x*(1.0f + erff(x*0.70710678118654752f));
}
__device__ __forceinline__ u16 f2bf(float f){
  u32 x = __float_as_uint(f);
  x += 0x7fffu + ((x>>16)&1u);           // RNE
  return (u16)(x>>16);
}

// ---------------- kernel 1: weight swizzle+bf16 (blocks 0..831) + FPS (blocks 832..959) ----
// A-frag layout: afrag[(kt*NT + ot)*64 + lane][j] = W[o = ot*16+(lane&15)][k = kt*32+(lane>>4)*8+j]
__global__ __launch_bounds__(256) void k_prep_fps(
    const float* __restrict__ dn_w, const float* __restrict__ ds_w, const float* __restrict__ sp_w,
    const float* __restrict__ coor,
    u16* __restrict__ wdb, u16* __restrict__ wcb, u16* __restrict__ wsb,
    int* __restrict__ fps_idx, int* __restrict__ nn_idx, float* __restrict__ coor_out)
{
  int blk = blockIdx.x, t = threadIdx.x;
  if (blk < 128){                       // dense MLP W [128o x 256k] -> 8kt x 8ot
    int w = blk*256 + t;
    int j=w&7, lane=(w>>3)&63, tile=w>>9;
    int kt=tile>>3, ot=tile&7;
    int o=ot*16+(lane&15), i=kt*32+(lane>>4)*8+j;
    wdb[w] = f2bf(dn_w[o*256+i]);
  } else if (blk < 320){                // conv W [128o x 384k] -> 12kt x 8ot
    int w = (blk-128)*256 + t;
    int j=w&7, lane=(w>>3)&63, tile=w>>9;
    int kt=tile>>3, ot=tile&7;
    int o=ot*16+(lane&15), k=kt*32+(lane>>4)*8+j;
    wcb[w] = f2bf(ds_w[o*384+k]);
  } else if (blk < 832){                // sparse W [256o x 512k] -> 16kt x 16ot
    int w = (blk-320)*256 + t;
    int j=w&7, lane=(w>>3)&63, tile=w>>9;
    int kt=tile>>4, ot=tile&15;
    int o=ot*16+(lane&15), i=kt*32+(lane>>4)*8+j;
    wsb[w] = f2bf(sp_w[o*512+i]);
  } else {
    // ---- wave-parallel FPS + NN + coor_out for b = blk-832 ----
    int b = blk - 832;
    __shared__ float Xs[32*33];         // padded: row j at j*33 (conflict-free broadcast)
    __shared__ int s_sel[16];
    for (int i=t;i<1024;i+=256) Xs[(i>>5)*33 + (i&31)] = coor[b*1024+i];
    __syncthreads();
    if (t < 64){
      int j = t & 31;                   // point id (both wave halves duplicate)
      float xc[32];
      #pragma unroll
      for (int c=0;c<32;c++) xc[c] = Xs[j*33+c];
      float dist = 3.0e38f;
      int far = 0;
      int selv[16];
      #pragma unroll
      for (int it=0; it<16; ++it){
        selv[it] = far;
        const float* fc = &Xs[far*33];
        float d=0.f;
        #pragma unroll
        for (int c=0;c<32;c++){ float df=xc[c]-fc[c]; d+=df*df; }
        dist = fminf(dist,d);
        // argmax over 32 lanes, first-index tie-break (matches jnp.argmax)
        float v=dist; int idx=j;
        #pragma unroll
        for (int off=16; off>=1; off>>=1){
          float v2=__shfl_xor(v,off,32); int i2=__shfl_xor(idx,off,32);
          if (v2>v || (v2==v && i2<idx)){ v=v2; idx=i2; }
        }
        far = idx;
      }
      // nearest other point per selected (knn[...,1]; knn[...,0] = self)
      #pragma unroll
      for (int it=0; it<16; ++it){
        int sel = selv[it];
        const float* fc = &Xs[sel*33];
        float d=0.f;
        #pragma unroll
        for (int c=0;c<32;c++){ float df=xc[c]-fc[c]; d+=df*df; }
        if (j==sel) d=3.0e38f;
        float v=d; int idx=j;
        #pragma unroll
        for (int off=16; off>=1; off>>=1){
          float v2=__shfl_xor(v,off,32); int i2=__shfl_xor(idx,off,32);
          if (v2<v || (v2==v && i2<idx)){ v=v2; idx=i2; }
        }
        if (t==0){ nn_idx[b*16+it]=idx; fps_idx[b*16+it]=sel; s_sel[it]=sel; }
      }
    }
    __syncthreads();
    for (int q=t;q<512;q+=256){
      int mm=q>>5, c=q&31;
      coor_out[b*512+q] = Xs[s_sel[mm]*33 + c];
    }
  }
}

// ---------------- kernel 2: fused sparse (blocks 0..255) + dense_conv (blocks 256..2303) ----
__global__ __launch_bounds__(256) void k_main(
    const float* __restrict__ sfea, const u16* __restrict__ wsb,
    const float* __restrict__ sp_b, const float* __restrict__ sp_g, const float* __restrict__ sp_be,
    const float* __restrict__ dfea, const u16* __restrict__ wdb,
    const float* __restrict__ dn_b, const float* __restrict__ dn_g, const float* __restrict__ dn_be,
    const u16* __restrict__ wcb,
    const float* __restrict__ ds_b, const float* __restrict__ ds_g, const float* __restrict__ ds_be,
    const int* __restrict__ fps_idx, const int* __restrict__ nn_idx,
    float* __restrict__ out_sp, float* __restrict__ out_dn)
{
  __shared__ char smem[20480];
  int blk=blockIdx.x;
  int t=threadIdx.x, lane=t&63, wv=t>>6, quad=lane>>4, col=lane&15;
  if (blk < 256){
    // ======== sparse branch: blk=(b, o-half). C = W[128o x 512i] * X[512i x 16m] ========
    int b=blk>>1, oh=blk&1;
    u16*   Xb = (u16*)smem;                      // [m][i] stride 520 (16640 B)
    float* P  = (float*)(smem+16640);            // Pb|Pg|Pe, 3x256 f32
    int*   SI = (int*)(smem+19712);              // s_ci[16], s_ni[16]
    if (t<16){ SI[t]=fps_idx[b*16+t]&31; SI[16+t]=nn_idx[b*16+t]&31; }
    P[t]=sp_b[t]; P[256+t]=sp_g[t]; P[512+t]=sp_be[t];
    __syncthreads();
    const float* row = sfea + b*8192 + t*32;     // channel t
    #pragma unroll
    for (int m=0;m<16;m++){
      float vc=row[SI[m]], vn=row[SI[16+m]];
      Xb[m*520 + t]       = f2bf(vn-vc);         // i<256: diff
      Xb[m*520 + 256 + t] = f2bf(vc);            // i>=256: ctr
    }
    __syncthreads();
    f32x4 accA[2]={}, accB[2]={};
    for (int kt=0;kt<8;kt++){                    // diff half
      bf16x8 bfr = *(const bf16x8*)&Xb[col*520 + kt*32 + quad*8];
      #pragma unroll
      for (int r=0;r<2;r++){
        int ot = oh*8 + wv + r*4;
        bf16x8 afr = *(const bf16x8*)&wsb[((kt*16+ot)*64+lane)*8];
        accA[r]=__builtin_amdgcn_mfma_f32_16x16x32_bf16(afr,bfr,accA[r],0,0,0);
      }
    }
    for (int kt=8;kt<16;kt++){                   // ctr half
      bf16x8 bfr = *(const bf16x8*)&Xb[col*520 + kt*32 + quad*8];
      #pragma unroll
      for (int r=0;r<2;r++){
        int ot = oh*8 + wv + r*4;
        bf16x8 afr = *(const bf16x8*)&wsb[((kt*16+ot)*64+lane)*8];
        accB[r]=__builtin_amdgcn_mfma_f32_16x16x32_bf16(afr,bfr,accB[r],0,0,0);
      }
    }
    #pragma unroll
    for (int r=0;r<2;r++){
      #pragma unroll
      for (int reg=0;reg<4;reg++){
        int o = oh*128 + (wv+r*4)*16 + quad*4 + reg;
        float bo=P[o], go=P[256+o], be=P[512+o];
        float k1 = accA[r][reg]+accB[r][reg]+bo; // k=1: [diff|ctr]
        float k0 = accB[r][reg]+bo;              // k=0: diff part exactly 0
        float v = fmaxf(gelu_f(go*(k1*BN_SCALE)+be), gelu_f(go*(k0*BN_SCALE)+be));
        out_sp[(b*256+o)*16 + col] = v;
      }
    }
  } else {
    // ======== dense branch: per (b,m): MLP [128x256]x[256x32] -> max_k -> im2col -> conv ========
    int bd=blk-256; int b=bd>>4, m=bd&15;
    u16* Vb = (u16*)smem;                 // phase 1: [32p][264] bf16 (16896 B)
    u16* Bc = (u16*)smem;                 // phase 2: [16x][392] bf16 im2col (12544 B, overlaps)
    float* P = (float*)(smem+16896);      // dn_b|dn_g|dn_be|ds_b|ds_g|ds_be|a0s, 7x128 f32
    int ci=fps_idx[bd]&31, ni=nn_idx[bd]&31;
    const float* Db = dfea + b*131072;    // dfea[b][c][s][x]: c*1024 + s*32 + x
    if (t<128){
      P[t]=dn_b[t]; P[128+t]=dn_g[t]; P[256+t]=dn_be[t];
      P[384+t]=ds_b[t]; P[512+t]=ds_g[t]; P[640+t]=ds_be[t];
    }
    for (int fp=t; fp<2048; fp+=256){
      int c=fp>>4, xp=fp&15, x=xp*2;
      float2 fc = *(const float2*)(Db + c*1024 + ci*32 + x);
      float2 fn = *(const float2*)(Db + c*1024 + ni*32 + x);
      // Vb[p][i]: p<16 diff, p>=16 ctr; i = (x&1)*128 + c
      Vb[xp*264 + c]            = f2bf(fn.x-fc.x);
      Vb[(16+xp)*264 + c]       = f2bf(fc.x);
      Vb[xp*264 + 128 + c]      = f2bf(fn.y-fc.y);
      Vb[(16+xp)*264 + 128 + c] = f2bf(fc.y);
    }
    __syncthreads();
    if (t<128) P[768+t] = gelu_f(P[128+t]*(P[t]*BN_SCALE)+P[256+t]);  // a0s[o] (k=0 diff value)
    // ---- dense MLP: C[128o x 32p], wave: otiles {wv, wv+4}, ptiles {0,1} ----
    f32x4 acc[2][2]={};
    for (int kt=0;kt<8;kt++){
      bf16x8 b0 = *(const bf16x8*)&Vb[ col     *264 + kt*32 + quad*8];
      bf16x8 b1 = *(const bf16x8*)&Vb[(16+col) *264 + kt*32 + quad*8];
      #pragma unroll
      for (int r=0;r<2;r++){
        int ot=wv+r*4;
        bf16x8 afr = *(const bf16x8*)&wdb[((kt*8+ot)*64+lane)*8];
        acc[r][0]=__builtin_amdgcn_mfma_f32_16x16x32_bf16(afr,b0,acc[r][0],0,0,0);
        acc[r][1]=__builtin_amdgcn_mfma_f32_16x16x32_bf16(afr,b1,acc[r][1],0,0,0);
      }
    }
    __syncthreads();                       // Vb dead -> reuse as Bc
    for (int q=t; q<3136; q+=256) ((u32*)Bc)[q]=0u;   // zero im2col (left pad x=0 tap0)
    __syncthreads();
    // ---- epilogue 1: bn+gelu+max_k, scatter S[o][p] into im2col Bc[x][o*3+tap] ----
    #pragma unroll
    for (int r=0;r<2;r++){
      #pragma unroll
      for (int pt=0;pt<2;pt++){
        #pragma unroll
        for (int reg=0;reg<4;reg++){
          int o = (wv+r*4)*16 + quad*4 + reg;
          int p = pt*16 + col;
          float bo=P[o], go=P[128+o], be=P[256+o];
          float val = gelu_f(go*((acc[r][pt][reg]+bo)*BN_SCALE)+be);
          if (pt==0) val = fmaxf(val, P[768+o]);     // p<16: max over k
          u16 bv = f2bf(val);
          // S[c=o][p] feeds conv taps: 2x-1+tap == p
          if (p&1){
            Bc[((p-1)>>1)*392 + o*3 + 2] = bv;
            if (p<31) Bc[((p+1)>>1)*392 + o*3 + 0] = bv;
          } else {
            Bc[(p>>1)*392 + o*3 + 1] = bv;
          }
        }
      }
    }
    __syncthreads();
    // ---- conv: C[128o x 16x] = Wc[128o x 384k] * Bc[384k x 16x] ----
    f32x4 cacc[2]={};
    for (int kt=0;kt<12;kt++){
      bf16x8 bfr = *(const bf16x8*)&Bc[col*392 + kt*32 + quad*8];
      #pragma unroll
      for (int r=0;r<2;r++){
        int ot=wv+r*4;
        bf16x8 afr = *(const bf16x8*)&wcb[((kt*8+ot)*64+lane)*8];
        cacc[r]=__builtin_amdgcn_mfma_f32_16x16x32_bf16(afr,bfr,cacc[r],0,0,0);
      }
    }
    #pragma unroll
    for (int r=0;r<2;r++){
      #pragma unroll
      for (int reg=0;reg<4;reg++){
        int o = (wv+r*4)*16 + quad*4 + reg;
        float cb=P[384+o], go=P[512+o], be=P[640+o];
        float val = gelu_f(go*((cacc[r][reg]+cb)*BN_SCALE)+be);
        out_dn[(b*128+o)*256 + m*16 + col] = val;
      }
    }
  }
}

extern "C" void kernel_launch(void* const* d_in, const int* in_sizes, int n_in,
                              void* d_out, int out_size, void* d_ws, size_t ws_size,
                              hipStream_t stream) {
  const float* sparse_fea = (const float*)d_in[0];
  const float* dense_fea  = (const float*)d_in[1];
  const float* stk_coor   = (const float*)d_in[2];
  // d_in[3] = n_stk_center (16, hardcoded)
  const float* sp_w  = (const float*)d_in[4];
  const float* sp_b  = (const float*)d_in[5];
  const float* sp_g  = (const float*)d_in[6];
  const float* sp_be = (const float*)d_in[7];
  const float* dn_w  = (const float*)d_in[8];
  const float* dn_b  = (const float*)d_in[9];
  const float* dn_g  = (const float*)d_in[10];
  const float* dn_be = (const float*)d_in[11];
  const float* ds_w  = (const float*)d_in[12];
  const float* ds_b  = (const float*)d_in[13];
  const float* ds_g  = (const float*)d_in[14];
  const float* ds_be = (const float*)d_in[15];

  float* out = (float*)d_out;
  // outputs: sparse [0, 524288) | dense [524288, 4718592) | coor [4718592, 4784128)
  int* fps_idx = (int*)d_ws;                              // [0, 16384) B
  int* nn_idx  = fps_idx + 2048;
  u16* wdb = (u16*)((char*)d_ws + 16384);                 // 64 KB  (8kt x 8ot)
  u16* wcb = (u16*)((char*)d_ws + 81920);                 // 96 KB  (12kt x 8ot)
  u16* wsb = (u16*)((char*)d_ws + 180224);                // 256 KB (16kt x 16ot)

  k_prep_fps<<<960, 256, 0, stream>>>(dn_w, ds_w, sp_w, stk_coor,
                                      wdb, wcb, wsb, fps_idx, nn_idx, out + 4718592);
  k_main    <<<2304, 256, 0, stream>>>(sparse_fea, wsb, sp_b, sp_g, sp_be,
                                       dense_fea, wdb, dn_b, dn_g, dn_be,
                                       wcb, ds_b, ds_g, ds_be,
                                       fps_idx, nn_idx, out, out + 524288);
}

// Round 7
// 172.068 us; speedup vs baseline: 3.5133x; 1.0430x over previous
//
#include <hip/hip_runtime.h>

// DownSample (fp32 in/out, bf16 MFMA internals), MI355X gfx950
// Shapes: B=128, n_stk=32, n_stk_pnt=32, COOR=32, m=16, k=2
// outputs: sparse_out [128,256,16] | dense_out [128,128,16,16] | coor_out [128,16,32]
//
// R7: prep split into k_weights + k_fps (diagnosis + pairwise-D FPS);
// k_main LDS 20.5->16.9KB (params staged into dead LDS) for 8 blocks/CU;
// XCD-locality block swizzle (all blocks of batch b on one XCD).

typedef unsigned short u16;
typedef unsigned int   u32;
typedef __attribute__((ext_vector_type(8))) short bf16x8;   // 4 VGPRs
typedef __attribute__((ext_vector_type(4))) float f32x4;

#define BN_SCALE 0.9999950000374997f   // 1/sqrt(1+1e-5)

__device__ __forceinline__ float gelu_f(float x){
  return 0.5f*x*(1.0f + erff(x*0.70710678118654752f));
}
__device__ __forceinline__ u16 f2bf(float f){
  u32 x = __float_as_uint(f);
  x += 0x7fffu + ((x>>16)&1u);           // RNE
  return (u16)(x>>16);
}

// ---------------- kernel 1a: weight swizzle + bf16 cast (832 blocks) ----------------
// A-frag layout: afrag[(kt*NT + ot)*64 + lane][j] = W[o = ot*16+(lane&15)][k = kt*32+(lane>>4)*8+j]
__global__ __launch_bounds__(256) void k_weights(
    const float* __restrict__ dn_w, const float* __restrict__ ds_w, const float* __restrict__ sp_w,
    u16* __restrict__ wdb, u16* __restrict__ wcb, u16* __restrict__ wsb)
{
  int blk = blockIdx.x, t = threadIdx.x;
  if (blk < 128){                       // dense MLP W [128o x 256k] -> 8kt x 8ot
    int w = blk*256 + t;
    int j=w&7, lane=(w>>3)&63, tile=w>>9;
    int kt=tile>>3, ot=tile&7;
    int o=ot*16+(lane&15), i=kt*32+((lane>>4)&3)*8+j;
    wdb[w] = f2bf(dn_w[o*256+i]);
  } else if (blk < 320){                // conv W [128o x 384k] -> 12kt x 8ot
    int w = (blk-128)*256 + t;
    int j=w&7, lane=(w>>3)&63, tile=w>>9;
    int kt=tile>>3, ot=tile&7;
    int o=ot*16+(lane&15), k=kt*32+((lane>>4)&3)*8+j;
    wcb[w] = f2bf(ds_w[o*384+k]);
  } else {                              // sparse W [256o x 512k] -> 16kt x 16ot
    int w = (blk-320)*256 + t;
    int j=w&7, lane=(w>>3)&63, tile=w>>9;
    int kt=tile>>4, ot=tile&15;
    int o=ot*16+(lane&15), i=kt*32+((lane>>4)&3)*8+j;
    wsb[w] = f2bf(sp_w[o*512+i]);
  }
}

// ---------------- kernel 1b: FPS + NN + coor_out (128 blocks, 256 threads) ----------------
__global__ __launch_bounds__(256) void k_fps(
    const float* __restrict__ coor,
    int* __restrict__ fps_idx, int* __restrict__ nn_idx, float* __restrict__ coor_out)
{
  int b = blockIdx.x, t = threadIdx.x;
  __shared__ float Xs[32*33];
  __shared__ float D[32*33];            // pairwise squared distances
  __shared__ int   s_sel[16];
  for (int i=t;i<1024;i+=256) Xs[(i>>5)*33 + (i&31)] = coor[b*1024+i];
  __syncthreads();
  // pairwise D: 1024 pairs, 4 per thread (ILP-4 FMA chains)
  #pragma unroll
  for (int k2=0;k2<4;k2++){
    int p=t+k2*256, i=p>>5, j=p&31;
    float d=0.f;
    #pragma unroll
    for (int c=0;c<32;c++){ float df=Xs[i*33+c]-Xs[j*33+c]; d+=df*df; }
    D[i*33+j]=d;
  }
  __syncthreads();
  if (t < 64){
    int j = t & 31;
    float dist = 3.0e38f;
    int far = 0;
    #pragma unroll
    for (int it=0; it<16; ++it){
      if (t==0) s_sel[it]=far;
      dist = fminf(dist, D[far*33+j]);
      float v=dist; int idx=j;              // argmax, first-index tie-break
      #pragma unroll
      for (int off=16; off>=1; off>>=1){
        float v2=__shfl_xor(v,off,32); int i2=__shfl_xor(idx,off,32);
        if (v2>v || (v2==v && i2<idx)){ v=v2; idx=i2; }
      }
      far = idx;
    }
    if (t==0){
      #pragma unroll
      for (int it=0;it<16;++it) fps_idx[b*16+it]=s_sel[it];
    }
  }
  __syncthreads();
  // NN per selected point, 4-way wave-parallel (wave w handles it = w*4+q)
  {
    int wv=t>>6, j=t&31;
    #pragma unroll
    for (int q=0;q<4;q++){
      int it = wv*4+q, sel = s_sel[it];
      float d = D[sel*33+j];
      if (j==sel) d=3.0e38f;
      float v=d; int idx=j;                 // argmin, first-index tie-break
      #pragma unroll
      for (int off=16; off>=1; off>>=1){
        float v2=__shfl_xor(v,off,32); int i2=__shfl_xor(idx,off,32);
        if (v2<v || (v2==v && i2<idx)){ v=v2; idx=i2; }
      }
      if ((t&63)==0) nn_idx[b*16+it]=idx;
    }
  }
  for (int q=t;q<512;q+=256){
    int mm=q>>5, c=q&31;
    coor_out[b*512+q] = Xs[s_sel[mm]*33 + c];
  }
}

// ---------------- kernel 2: fused sparse (blocks 0..255) + dense_conv (blocks 256..2303) ----------------
// Block swizzle keeps all blocks of a batch b on one XCD (blk % 8 == b & 7).
__global__ __launch_bounds__(256) void k_main(
    const float* __restrict__ sfea, const u16* __restrict__ wsb,
    const float* __restrict__ sp_b, const float* __restrict__ sp_g, const float* __restrict__ sp_be,
    const float* __restrict__ dfea, const u16* __restrict__ wdb,
    const float* __restrict__ dn_b, const float* __restrict__ dn_g, const float* __restrict__ dn_be,
    const u16* __restrict__ wcb,
    const float* __restrict__ ds_b, const float* __restrict__ ds_g, const float* __restrict__ ds_be,
    const int* __restrict__ fps_idx, const int* __restrict__ nn_idx,
    float* __restrict__ out_sp, float* __restrict__ out_dn)
{
  __shared__ char smem[16896];
  int blk=blockIdx.x;
  int t=threadIdx.x, lane=t&63, wv=t>>6, quad=lane>>4, col=lane&15;
  if (blk < 256){
    // ======== sparse: b = ((blk>>4)<<3)|(blk&7), oh = (blk>>3)&1 ========
    int b = ((blk>>4)<<3) | (blk&7), oh = (blk>>3)&1;
    u16*   Xb = (u16*)smem;                      // [m][i] stride 520 (16640 B)
    float* P  = (float*)smem;                    // epilogue: Pb|Pg|Pe 3x256 (Xb dead)
    __shared__ int SI[32];
    if (t<16){ SI[t]=fps_idx[b*16+t]&31; SI[16+t]=nn_idx[b*16+t]&31; }
    __syncthreads();
    const float* row = sfea + b*8192 + t*32;     // channel t
    #pragma unroll
    for (int m=0;m<16;m++){
      float vc=row[SI[m]], vn=row[SI[16+m]];
      Xb[m*520 + t]       = f2bf(vn-vc);         // i<256: diff
      Xb[m*520 + 256 + t] = f2bf(vc);            // i>=256: ctr
    }
    __syncthreads();
    f32x4 accA[2]={}, accB[2]={};
    for (int kt=0;kt<8;kt++){                    // diff half
      bf16x8 bfr = *(const bf16x8*)&Xb[col*520 + kt*32 + quad*8];
      #pragma unroll
      for (int r=0;r<2;r++){
        int ot = oh*8 + wv + r*4;
        bf16x8 afr = *(const bf16x8*)&wsb[((kt*16+ot)*64+lane)*8];
        accA[r]=__builtin_amdgcn_mfma_f32_16x16x32_bf16(afr,bfr,accA[r],0,0,0);
      }
    }
    for (int kt=8;kt<16;kt++){                   // ctr half
      bf16x8 bfr = *(const bf16x8*)&Xb[col*520 + kt*32 + quad*8];
      #pragma unroll
      for (int r=0;r<2;r++){
        int ot = oh*8 + wv + r*4;
        bf16x8 afr = *(const bf16x8*)&wsb[((kt*16+ot)*64+lane)*8];
        accB[r]=__builtin_amdgcn_mfma_f32_16x16x32_bf16(afr,bfr,accB[r],0,0,0);
      }
    }
    __syncthreads();                             // Xb dead -> params
    P[t]=sp_b[t]; P[256+t]=sp_g[t]; P[512+t]=sp_be[t];
    __syncthreads();
    #pragma unroll
    for (int r=0;r<2;r++){
      #pragma unroll
      for (int reg=0;reg<4;reg++){
        int o = oh*128 + (wv+r*4)*16 + quad*4 + reg;
        float bo=P[o], go=P[256+o], be=P[512+o];
        float k1 = accA[r][reg]+accB[r][reg]+bo; // k=1: [diff|ctr]
        float k0 = accB[r][reg]+bo;              // k=0: diff part exactly 0
        float v = fmaxf(gelu_f(go*(k1*BN_SCALE)+be), gelu_f(go*(k0*BN_SCALE)+be));
        out_sp[(b*256+o)*16 + col] = v;
      }
    }
  } else {
    // ======== dense: d = blk-256; b = ((d>>7)<<3)|(d&7), m = (d>>3)&15 ========
    int d=blk-256;
    int b = ((d>>7)<<3) | (d&7), m = (d>>3)&15;
    u16* Vb = (u16*)smem;                 // phase 1: [32p][264] bf16 (16896 B)
    u16* Bc = (u16*)smem;                 // phase 2: [16x][392] bf16 im2col (12544 B)
    float* P = (float*)(smem+12544);      // phase 2: dn_b|dn_g|dn_be|ds_b|ds_g|ds_be|a0s (3584 B)
    int mi = b*16+m;
    int ci=fps_idx[mi]&31, ni=nn_idx[mi]&31;
    const float* Db = dfea + b*131072;    // dfea[b][c][s][x]: c*1024 + s*32 + x
    for (int fp=t; fp<2048; fp+=256){
      int c=fp>>4, xp=fp&15, x=xp*2;
      float2 fc = *(const float2*)(Db + c*1024 + ci*32 + x);
      float2 fn = *(const float2*)(Db + c*1024 + ni*32 + x);
      // Vb[p][i]: p<16 diff, p>=16 ctr; i = (x&1)*128 + c
      Vb[xp*264 + c]            = f2bf(fn.x-fc.x);
      Vb[(16+xp)*264 + c]       = f2bf(fc.x);
      Vb[xp*264 + 128 + c]      = f2bf(fn.y-fc.y);
      Vb[(16+xp)*264 + 128 + c] = f2bf(fc.y);
    }
    __syncthreads();
    // ---- dense MLP: C[128o x 32p], wave: otiles {wv, wv+4}, ptiles {0,1} ----
    f32x4 acc[2][2]={};
    for (int kt=0;kt<8;kt++){
      bf16x8 b0 = *(const bf16x8*)&Vb[ col     *264 + kt*32 + quad*8];
      bf16x8 b1 = *(const bf16x8*)&Vb[(16+col) *264 + kt*32 + quad*8];
      #pragma unroll
      for (int r=0;r<2;r++){
        int ot=wv+r*4;
        bf16x8 afr = *(const bf16x8*)&wdb[((kt*8+ot)*64+lane)*8];
        acc[r][0]=__builtin_amdgcn_mfma_f32_16x16x32_bf16(afr,b0,acc[r][0],0,0,0);
        acc[r][1]=__builtin_amdgcn_mfma_f32_16x16x32_bf16(afr,b1,acc[r][1],0,0,0);
      }
    }
    __syncthreads();                       // Vb dead -> Bc + params
    for (int q=t; q<3136; q+=256) ((u32*)Bc)[q]=0u;   // zero im2col (left pad)
    if (t<128){
      float b0=dn_b[t], g0=dn_g[t], e0=dn_be[t];
      P[t]=b0; P[128+t]=g0; P[256+t]=e0;
      P[384+t]=ds_b[t]; P[512+t]=ds_g[t]; P[640+t]=ds_be[t];
      P[768+t]=gelu_f(g0*(b0*BN_SCALE)+e0);           // a0 (k=0 diff value)
    }
    __syncthreads();
    // ---- epilogue 1: bn+gelu+max_k, scatter S[o][p] into im2col Bc[x][o*3+tap] ----
    #pragma unroll
    for (int r=0;r<2;r++){
      #pragma unroll
      for (int pt=0;pt<2;pt++){
        #pragma unroll
        for (int reg=0;reg<4;reg++){
          int o = (wv+r*4)*16 + quad*4 + reg;
          int p = pt*16 + col;
          float bo=P[o], go=P[128+o], be=P[256+o];
          float val = gelu_f(go*((acc[r][pt][reg]+bo)*BN_SCALE)+be);
          if (pt==0) val = fmaxf(val, P[768+o]);     // p<16: max over k
          u16 bv = f2bf(val);
          // S[c=o][p] feeds conv taps: 2x-1+tap == p
          if (p&1){
            Bc[((p-1)>>1)*392 + o*3 + 2] = bv;
            if (p<31) Bc[((p+1)>>1)*392 + o*3 + 0] = bv;
          } else {
            Bc[(p>>1)*392 + o*3 + 1] = bv;
          }
        }
      }
    }
    __syncthreads();
    // ---- conv: C[128o x 16x] = Wc[128o x 384k] * Bc[384k x 16x] ----
    f32x4 cacc[2]={};
    for (int kt=0;kt<12;kt++){
      bf16x8 bfr = *(const bf16x8*)&Bc[col*392 + kt*32 + quad*8];
      #pragma unroll
      for (int r=0;r<2;r++){
        int ot=wv+r*4;
        bf16x8 afr = *(const bf16x8*)&wcb[((kt*8+ot)*64+lane)*8];
        cacc[r]=__builtin_amdgcn_mfma_f32_16x16x32_bf16(afr,bfr,cacc[r],0,0,0);
      }
    }
    #pragma unroll
    for (int r=0;r<2;r++){
      #pragma unroll
      for (int reg=0;reg<4;reg++){
        int o = (wv+r*4)*16 + quad*4 + reg;
        float cb=P[384+o], go=P[512+o], be=P[640+o];
        float val = gelu_f(go*((cacc[r][reg]+cb)*BN_SCALE)+be);
        out_dn[(b*128+o)*256 + m*16 + col] = val;
      }
    }
  }
}

extern "C" void kernel_launch(void* const* d_in, const int* in_sizes, int n_in,
                              void* d_out, int out_size, void* d_ws, size_t ws_size,
                              hipStream_t stream) {
  const float* sparse_fea = (const float*)d_in[0];
  const float* dense_fea  = (const float*)d_in[1];
  const float* stk_coor   = (const float*)d_in[2];
  // d_in[3] = n_stk_center (16, hardcoded)
  const float* sp_w  = (const float*)d_in[4];
  const float* sp_b  = (const float*)d_in[5];
  const float* sp_g  = (const float*)d_in[6];
  const float* sp_be = (const float*)d_in[7];
  const float* dn_w  = (const float*)d_in[8];
  const float* dn_b  = (const float*)d_in[9];
  const float* dn_g  = (const float*)d_in[10];
  const float* dn_be = (const float*)d_in[11];
  const float* ds_w  = (const float*)d_in[12];
  const float* ds_b  = (const float*)d_in[13];
  const float* ds_g  = (const float*)d_in[14];
  const float* ds_be = (const float*)d_in[15];

  float* out = (float*)d_out;
  // outputs: sparse [0, 524288) | dense [524288, 4718592) | coor [4718592, 4784128)
  int* fps_idx = (int*)d_ws;                              // [0, 16384) B
  int* nn_idx  = fps_idx + 2048;
  u16* wdb = (u16*)((char*)d_ws + 16384);                 // 64 KB  (8kt x 8ot)
  u16* wcb = (u16*)((char*)d_ws + 81920);                 // 96 KB  (12kt x 8ot)
  u16* wsb = (u16*)((char*)d_ws + 180224);                // 256 KB (16kt x 16ot)

  k_fps    <<<128, 256, 0, stream>>>(stk_coor, fps_idx, nn_idx, out + 4718592);
  k_weights<<<832, 256, 0, stream>>>(dn_w, ds_w, sp_w, wdb, wcb, wsb);
  k_main   <<<2304, 256, 0, stream>>>(sparse_fea, wsb, sp_b, sp_g, sp_be,
                                      dense_fea, wdb, dn_b, dn_g, dn_be,
                                      wcb, ds_b, ds_g, ds_be,
                                      fps_idx, nn_idx, out, out + 524288);
}

// Round 8
// 167.344 us; speedup vs baseline: 3.6125x; 1.0282x over previous
//
#include <hip/hip_runtime.h>

// DownSample (fp32 in/out, bf16 MFMA internals), MI355X gfx950
// Shapes: B=128, n_stk=32, n_stk_pnt=32, COOR=32, m=16, k=2
// outputs: sparse_out [128,256,16] | dense_out [128,128,16,16] | coor_out [128,16,32]
//
// R8: dense blocks do 2 m each, sparse blocks 2 b each (2-4 MFMAs per A-frag
// load, half the barrier phases); all K-loops force-unrolled for load batching;
// prep kernels merged.

typedef unsigned short u16;
typedef unsigned int   u32;
typedef __attribute__((ext_vector_type(8))) short bf16x8;   // 4 VGPRs
typedef __attribute__((ext_vector_type(4))) float f32x4;

#define BN_SCALE 0.9999950000374997f   // 1/sqrt(1+1e-5)

__device__ __forceinline__ float gelu_f(float x){
  return 0.5f*x*(1.0f + erff(x*0.70710678118654752f));
}
__device__ __forceinline__ u16 f2bf(float f){
  u32 x = __float_as_uint(f);
  x += 0x7fffu + ((x>>16)&1u);           // RNE
  return (u16)(x>>16);
}

// ---------------- kernel 1: weight swizzle (blocks 0..831) + FPS (832..959) ----------------
// A-frag layout: afrag[(kt*NT + ot)*64 + lane][j] = W[o = ot*16+(lane&15)][k = kt*32+((lane>>4)&3)*8+j]
__global__ __launch_bounds__(256) void k_prep(
    const float* __restrict__ dn_w, const float* __restrict__ ds_w, const float* __restrict__ sp_w,
    const float* __restrict__ coor,
    u16* __restrict__ wdb, u16* __restrict__ wcb, u16* __restrict__ wsb,
    int* __restrict__ fps_idx, int* __restrict__ nn_idx, float* __restrict__ coor_out)
{
  int blk = blockIdx.x, t = threadIdx.x;
  if (blk < 128){                       // dense MLP W [128o x 256k] -> 8kt x 8ot
    int w = blk*256 + t;
    int j=w&7, lane=(w>>3)&63, tile=w>>9;
    int kt=tile>>3, ot=tile&7;
    int o=ot*16+(lane&15), i=kt*32+((lane>>4)&3)*8+j;
    wdb[w] = f2bf(dn_w[o*256+i]);
  } else if (blk < 320){                // conv W [128o x 384k] -> 12kt x 8ot
    int w = (blk-128)*256 + t;
    int j=w&7, lane=(w>>3)&63, tile=w>>9;
    int kt=tile>>3, ot=tile&7;
    int o=ot*16+(lane&15), k=kt*32+((lane>>4)&3)*8+j;
    wcb[w] = f2bf(ds_w[o*384+k]);
  } else if (blk < 832){                // sparse W [256o x 512k] -> 16kt x 16ot
    int w = (blk-320)*256 + t;
    int j=w&7, lane=(w>>3)&63, tile=w>>9;
    int kt=tile>>4, ot=tile&15;
    int o=ot*16+(lane&15), i=kt*32+((lane>>4)&3)*8+j;
    wsb[w] = f2bf(sp_w[o*512+i]);
  } else {
    // ---- FPS + NN + coor_out for b = blk-832 ----
    int b = blk - 832;
    __shared__ float Xs[32*33];
    __shared__ float D[32*33];
    __shared__ int   s_sel[16];
    for (int i=t;i<1024;i+=256) Xs[(i>>5)*33 + (i&31)] = coor[b*1024+i];
    __syncthreads();
    #pragma unroll
    for (int k2=0;k2<4;k2++){
      int p=t+k2*256, i=p>>5, j=p&31;
      float d=0.f;
      #pragma unroll
      for (int c=0;c<32;c++){ float df=Xs[i*33+c]-Xs[j*33+c]; d+=df*df; }
      D[i*33+j]=d;
    }
    __syncthreads();
    if (t < 64){
      int j = t & 31;
      float dist = 3.0e38f;
      int far = 0;
      #pragma unroll
      for (int it=0; it<16; ++it){
        if (t==0) s_sel[it]=far;
        dist = fminf(dist, D[far*33+j]);
        float v=dist; int idx=j;              // argmax, first-index tie-break
        #pragma unroll
        for (int off=16; off>=1; off>>=1){
          float v2=__shfl_xor(v,off,32); int i2=__shfl_xor(idx,off,32);
          if (v2>v || (v2==v && i2<idx)){ v=v2; idx=i2; }
        }
        far = idx;
      }
      if (t==0){
        #pragma unroll
        for (int it=0;it<16;++it) fps_idx[b*16+it]=s_sel[it];
      }
    }
    __syncthreads();
    {
      int wv=t>>6, j=t&31;
      #pragma unroll
      for (int q=0;q<4;q++){
        int it = wv*4+q, sel = s_sel[it];
        float d = D[sel*33+j];
        if (j==sel) d=3.0e38f;
        float v=d; int idx=j;                 // argmin, first-index tie-break
        #pragma unroll
        for (int off=16; off>=1; off>>=1){
          float v2=__shfl_xor(v,off,32); int i2=__shfl_xor(idx,off,32);
          if (v2<v || (v2==v && i2<idx)){ v=v2; idx=i2; }
        }
        if ((t&63)==0) nn_idx[b*16+it]=idx;
      }
    }
    for (int q=t;q<512;q+=256){
      int mm=q>>5, c=q&31;
      coor_out[b*512+q] = Xs[s_sel[mm]*33 + c];
    }
  }
}

// ---------------- kernel 2: fused sparse (blocks 0..63, 2 b each) + dense (64..1087, 2 m each) ----
__global__ __launch_bounds__(256) void k_main(
    const float* __restrict__ sfea, const u16* __restrict__ wsb,
    const float* __restrict__ sp_b, const float* __restrict__ sp_g, const float* __restrict__ sp_be,
    const float* __restrict__ dfea, const u16* __restrict__ wdb,
    const float* __restrict__ dn_b, const float* __restrict__ dn_g, const float* __restrict__ dn_be,
    const u16* __restrict__ wcb,
    const float* __restrict__ ds_b, const float* __restrict__ ds_g, const float* __restrict__ ds_be,
    const int* __restrict__ fps_idx, const int* __restrict__ nn_idx,
    float* __restrict__ out_sp, float* __restrict__ out_dn)
{
  __shared__ char smem[36352];
  __shared__ int SI[64];
  int blk=blockIdx.x;
  int t=threadIdx.x, lane=t&63, wv=t>>6, quad=lane>>4, col=lane&15;
  if (blk < 64){
    // ======== sparse: b in {2*blk, 2*blk+1}; C = W[256o x 512i] * X[512i x 16m] x2 ========
    int b0 = blk*2;
    u16*   Xb = (u16*)smem;                      // 2 x [16m][520] u16 = 33280 B
    float* P  = (float*)(smem+33280);            // Pb|Pg|Pe 3x256 f32
    if (t<64){
      int bb=t>>5, q=t&31, b=b0+bb;
      SI[t] = ((q<16) ? fps_idx[b*16+q] : nn_idx[b*16+(q-16)]) & 31;
    }
    P[t]=sp_b[t]; P[256+t]=sp_g[t]; P[512+t]=sp_be[t];
    __syncthreads();
    #pragma unroll
    for (int bb=0;bb<2;bb++){
      const float* row = sfea + (b0+bb)*8192 + t*32;   // channel t
      #pragma unroll
      for (int m=0;m<16;m++){
        float vc=row[SI[bb*32+m]], vn=row[SI[bb*32+16+m]];
        Xb[bb*8320 + m*520 + t]       = f2bf(vn-vc);   // i<256: diff
        Xb[bb*8320 + m*520 + 256 + t] = f2bf(vc);      // i>=256: ctr
      }
    }
    __syncthreads();
    #pragma unroll
    for (int oh=0;oh<2;oh++){
      f32x4 accA[2][2]={}, accB[2][2]={};        // [bb][r]
      #pragma unroll
      for (int kt=0;kt<16;kt++){
        bf16x8 bf0 = *(const bf16x8*)&Xb[        col*520 + kt*32 + quad*8];
        bf16x8 bf1 = *(const bf16x8*)&Xb[8320 +  col*520 + kt*32 + quad*8];
        #pragma unroll
        for (int r=0;r<2;r++){
          bf16x8 afr = *(const bf16x8*)&wsb[((kt*16 + oh*8 + wv + r*4)*64+lane)*8];
          if (kt<8){
            accA[0][r]=__builtin_amdgcn_mfma_f32_16x16x32_bf16(afr,bf0,accA[0][r],0,0,0);
            accA[1][r]=__builtin_amdgcn_mfma_f32_16x16x32_bf16(afr,bf1,accA[1][r],0,0,0);
          } else {
            accB[0][r]=__builtin_amdgcn_mfma_f32_16x16x32_bf16(afr,bf0,accB[0][r],0,0,0);
            accB[1][r]=__builtin_amdgcn_mfma_f32_16x16x32_bf16(afr,bf1,accB[1][r],0,0,0);
          }
        }
      }
      #pragma unroll
      for (int bb=0;bb<2;bb++){
        #pragma unroll
        for (int r=0;r<2;r++){
          #pragma unroll
          for (int reg=0;reg<4;reg++){
            int o = oh*128 + (wv+r*4)*16 + quad*4 + reg;
            float bo=P[o], go=P[256+o], be=P[512+o];
            float k1 = accA[bb][r][reg]+accB[bb][r][reg]+bo;  // k=1: [diff|ctr]
            float k0 = accB[bb][r][reg]+bo;                   // k=0: diff part exactly 0
            float v = fmaxf(gelu_f(go*(k1*BN_SCALE)+be), gelu_f(go*(k0*BN_SCALE)+be));
            out_sp[((b0+bb)*256+o)*16 + col] = v;
          }
        }
      }
    }
  } else {
    // ======== dense: d=blk-64; b=((d>>6)<<3)|(d&7); m-pair mp=(d>>3)&7 ========
    int d=blk-64;
    int b = ((d>>6)<<3) | (d&7), m0 = ((d>>3)&7)*2;
    u16* Vb = (u16*)smem;                 // phase 1: 2 x [32p][264] bf16 = 33792 B
    u16* Bc = (u16*)smem;                 // phase 2: 2 x [16x][392] bf16 = 25088 B
    float* P = (float*)(smem+25088);      // phase 2: dn_b|dn_g|dn_be|ds_b|ds_g|ds_be|a0 (3584 B)
    int ci0=fps_idx[b*16+m0]&31,   ni0=nn_idx[b*16+m0]&31;
    int ci1=fps_idx[b*16+m0+1]&31, ni1=nn_idx[b*16+m0+1]&31;
    const float* Db = dfea + b*131072;    // dfea[b][c][s][x]: c*1024 + s*32 + x
    #pragma unroll
    for (int ld=0; ld<8; ld++){
      int fp = t + ld*256;                // 0..2047
      int mi = fp>>10, idx = fp&1023, c = idx>>3, x = (idx&7)*4;
      int ci = mi ? ci1 : ci0, ni = mi ? ni1 : ni0;
      float4 fc4 = *(const float4*)(Db + c*1024 + ci*32 + x);
      float4 fn4 = *(const float4*)(Db + c*1024 + ni*32 + x);
      u16* VbM = Vb + mi*8448;
      #pragma unroll
      for (int e=0;e<4;e++){
        int xx=x+e, dp=xx&1, p=xx>>1;
        float fc=((const float*)&fc4)[e], fn=((const float*)&fn4)[e];
        VbM[p*264 + dp*128 + c]      = f2bf(fn-fc);   // diff cols p<16
        VbM[(16+p)*264 + dp*128 + c] = f2bf(fc);      // ctr cols p>=16
      }
    }
    __syncthreads();
    // ---- dense MLP: C[128o x 32p] for both m; acc[r][mi*2+pt] ----
    f32x4 acc[2][4]={};
    #pragma unroll
    for (int kt=0;kt<8;kt++){
      bf16x8 bfr[4];
      #pragma unroll
      for (int mi=0;mi<2;mi++)
        #pragma unroll
        for (int pt=0;pt<2;pt++)
          bfr[mi*2+pt] = *(const bf16x8*)&Vb[mi*8448 + (pt*16+col)*264 + kt*32 + quad*8];
      #pragma unroll
      for (int r=0;r<2;r++){
        bf16x8 afr = *(const bf16x8*)&wdb[((kt*8+wv+r*4)*64+lane)*8];
        #pragma unroll
        for (int q=0;q<4;q++)
          acc[r][q]=__builtin_amdgcn_mfma_f32_16x16x32_bf16(afr,bfr[q],acc[r][q],0,0,0);
      }
    }
    __syncthreads();                       // Vb dead -> Bc + P
    if (t<128){
      float b0v=dn_b[t], g0=dn_g[t], e0=dn_be[t];
      P[t]=b0v; P[128+t]=g0; P[256+t]=e0;
      P[384+t]=ds_b[t]; P[512+t]=ds_g[t]; P[640+t]=ds_be[t];
      P[768+t]=gelu_f(g0*(b0v*BN_SCALE)+e0);           // a0 (k=0 diff value)
    }
    { int mi=t>>7, o=t&127; Bc[mi*6272 + o*3] = 0; }   // only unwritten im2col slot: x=0,tap0
    __syncthreads();
    // ---- epilogue 1: bn+gelu+max_k, scatter S[o][p] -> im2col Bc[x][o*3+tap] ----
    #pragma unroll
    for (int r=0;r<2;r++){
      #pragma unroll
      for (int mi=0;mi<2;mi++){
        u16* BcM = Bc + mi*6272;
        #pragma unroll
        for (int pt=0;pt<2;pt++){
          #pragma unroll
          for (int reg=0;reg<4;reg++){
            int o = (wv+r*4)*16 + quad*4 + reg;
            int p = pt*16 + col;
            float bo=P[o], go=P[128+o], be=P[256+o];
            float val = gelu_f(go*((acc[r][mi*2+pt][reg]+bo)*BN_SCALE)+be);
            if (pt==0) val = fmaxf(val, P[768+o]);     // p<16: max over k
            u16 bv = f2bf(val);
            if (p&1){
              BcM[((p-1)>>1)*392 + o*3 + 2] = bv;
              if (p<31) BcM[((p+1)>>1)*392 + o*3 + 0] = bv;
            } else {
              BcM[(p>>1)*392 + o*3 + 1] = bv;
            }
          }
        }
      }
    }
    __syncthreads();
    // ---- conv: C[128o x 16x] = Wc[128o x 384k] * Bc[384k x 16x], both m ----
    f32x4 cacc[2][2]={};
    #pragma unroll
    for (int kt=0;kt<12;kt++){
      bf16x8 cb0 = *(const bf16x8*)&Bc[       col*392 + kt*32 + quad*8];
      bf16x8 cb1 = *(const bf16x8*)&Bc[6272 + col*392 + kt*32 + quad*8];
      #pragma unroll
      for (int r=0;r<2;r++){
        bf16x8 afr = *(const bf16x8*)&wcb[((kt*8+wv+r*4)*64+lane)*8];
        cacc[r][0]=__builtin_amdgcn_mfma_f32_16x16x32_bf16(afr,cb0,cacc[r][0],0,0,0);
        cacc[r][1]=__builtin_amdgcn_mfma_f32_16x16x32_bf16(afr,cb1,cacc[r][1],0,0,0);
      }
    }
    #pragma unroll
    for (int r=0;r<2;r++){
      #pragma unroll
      for (int mi=0;mi<2;mi++){
        #pragma unroll
        for (int reg=0;reg<4;reg++){
          int o = (wv+r*4)*16 + quad*4 + reg;
          float val = gelu_f(P[512+o]*((cacc[r][mi][reg]+P[384+o])*BN_SCALE)+P[640+o]);
          out_dn[(b*128+o)*256 + (m0+mi)*16 + col] = val;
        }
      }
    }
  }
}

extern "C" void kernel_launch(void* const* d_in, const int* in_sizes, int n_in,
                              void* d_out, int out_size, void* d_ws, size_t ws_size,
                              hipStream_t stream) {
  const float* sparse_fea = (const float*)d_in[0];
  const float* dense_fea  = (const float*)d_in[1];
  const float* stk_coor   = (const float*)d_in[2];
  // d_in[3] = n_stk_center (16, hardcoded)
  const float* sp_w  = (const float*)d_in[4];
  const float* sp_b  = (const float*)d_in[5];
  const float* sp_g  = (const float*)d_in[6];
  const float* sp_be = (const float*)d_in[7];
  const float* dn_w  = (const float*)d_in[8];
  const float* dn_b  = (const float*)d_in[9];
  const float* dn_g  = (const float*)d_in[10];
  const float* dn_be = (const float*)d_in[11];
  const float* ds_w  = (const float*)d_in[12];
  const float* ds_b  = (const float*)d_in[13];
  const float* ds_g  = (const float*)d_in[14];
  const float* ds_be = (const float*)d_in[15];

  float* out = (float*)d_out;
  // outputs: sparse [0, 524288) | dense [524288, 4718592) | coor [4718592, 4784128)
  int* fps_idx = (int*)d_ws;                              // [0, 16384) B
  int* nn_idx  = fps_idx + 2048;
  u16* wdb = (u16*)((char*)d_ws + 16384);                 // 64 KB  (8kt x 8ot)
  u16* wcb = (u16*)((char*)d_ws + 81920);                 // 96 KB  (12kt x 8ot)
  u16* wsb = (u16*)((char*)d_ws + 180224);                // 256 KB (16kt x 16ot)

  k_prep<<<960, 256, 0, stream>>>(dn_w, ds_w, sp_w, stk_coor,
                                  wdb, wcb, wsb, fps_idx, nn_idx, out + 4718592);
  k_main<<<1088, 256, 0, stream>>>(sparse_fea, wsb, sp_b, sp_g, sp_be,
                                   dense_fea, wdb, dn_b, dn_g, dn_be,
                                   wcb, ds_b, ds_g, ds_be,
                                   fps_idx, nn_idx, out, out + 524288);
}